// Round 17
// baseline (415.772 us; speedup 1.0000x reference)
//
#include <hip/hip_runtime.h>
#include <hip/hip_bf16.h>
#include <hip/hip_fp16.h>
#include <hip/hip_fp8.h>

#define N_B 16
#define C_DIM 256
#define HW 4096
#define M_TOT (N_B*HW)          // 65536 global rows
#define K_A 512
#define TEMP_INV (1.0f/0.3f)
#define EPS_SK 1e-12f

typedef _Float16 f16x8 __attribute__((ext_vector_type(8)));
typedef _Float16 f16x4 __attribute__((ext_vector_type(4)));
typedef float f32x4 __attribute__((ext_vector_type(4)));
typedef float f32x2 __attribute__((ext_vector_type(2)));

#if defined(__has_builtin)
#if __has_builtin(__builtin_amdgcn_cvt_pk_fp8_f32) && __has_builtin(__builtin_amdgcn_cvt_pk_f32_fp8)
#define HW_FP8 1
#endif
#endif

// natural column j -> stored slot (4x16 transpose within each 64-block); A8, S, SXv
// all live in slot space. gemm2 contracts in slot order on BOTH operands -> exact.
__device__ __forceinline__ int vperm(int j){
    return (j & ~63) | ((j & 15) << 2) | ((j & 63) >> 4);
}
// inverse: slot -> natural j within the 64-block
__device__ __forceinline__ int ivp(int s){
    return (s & ~63) | ((s & 3) << 4) | ((s & 63) >> 2);
}

#define GLOBAL_AS __attribute__((address_space(1)))
#define LDS_AS __attribute__((address_space(3)))
__device__ __forceinline__ void gload_lds16(const void* g, void* l){
    __builtin_amdgcn_global_load_lds((GLOBAL_AS const void*)g, (LDS_AS void*)l, 16, 0, 0);
}

// decode 8 fp8 (uint2) -> f16x8, exact (e4m3 values are exactly representable in fp16)
__device__ __forceinline__ f16x8 fp8x8_to_f16x8(uint2 a){
    f16x8 h;
#ifdef HW_FP8
    f32x2 q0 = __builtin_amdgcn_cvt_pk_f32_fp8((int)a.x, false);
    f32x2 q1 = __builtin_amdgcn_cvt_pk_f32_fp8((int)a.x, true);
    f32x2 q2 = __builtin_amdgcn_cvt_pk_f32_fp8((int)a.y, false);
    f32x2 q3 = __builtin_amdgcn_cvt_pk_f32_fp8((int)a.y, true);
    h[0]=(_Float16)q0[0]; h[1]=(_Float16)q0[1]; h[2]=(_Float16)q1[0]; h[3]=(_Float16)q1[1];
    h[4]=(_Float16)q2[0]; h[5]=(_Float16)q2[1]; h[6]=(_Float16)q3[0]; h[7]=(_Float16)q3[1];
#else
    union { uint2 u; __hip_fp8_e4m3 b8[8]; } cv; cv.u = a;
    #pragma unroll
    for (int e = 0; e < 8; ++e) h[e] = (_Float16)(float)cv.b8[e];
#endif
    return h;
}

// ---------------- fused: read x once -> L2 norm -> Lt[n][hw][c] fp16; zero S[4][512] ----------------
__global__ __launch_bounds__(256) void k_normtrans(const float* __restrict__ x,
                                                   _Float16* __restrict__ Lt,
                                                   float* __restrict__ S){
    __shared__ float tl[32][257];
    __shared__ float red[8][32];
    __shared__ float invs[32];
    int n   = blockIdx.x >> 7;           // 2048 blocks: 16 n x 128 hw-chunks of 32
    int hw0 = (blockIdx.x & 127) * 32;
    if (blockIdx.x == 0){
        #pragma unroll
        for (int q = 0; q < 8; ++q) S[threadIdx.x + q*256] = 0.0f;
    }
    int tx4 = threadIdx.x & 7;           // hw quad
    int cy  = threadIdx.x >> 3;          // 0..31
    const float* px = x + ((size_t)(n*C_DIM + cy))*HW + hw0 + tx4*4;
    #pragma unroll
    for (int r = 0; r < 8; ++r){
        float4 xv = *(const float4*)(px + (size_t)(r*32)*HW);
        int c = cy + r*32;
        tl[tx4*4+0][c] = xv.x;
        tl[tx4*4+1][c] = xv.y;
        tl[tx4*4+2][c] = xv.z;
        tl[tx4*4+3][c] = xv.w;
    }
    __syncthreads();
    int tx = threadIdx.x & 31, ty = threadIdx.x >> 5;   // ty 0..7
    float ss = 0.f;
    #pragma unroll
    for (int cc = 0; cc < 32; ++cc){
        float tv = tl[tx][cc*8 + ty];
        ss += tv*tv;
    }
    red[ty][tx] = ss;
    __syncthreads();
    if (ty == 0){
        float s = red[0][tx]+red[1][tx]+red[2][tx]+red[3][tx]
                + red[4][tx]+red[5][tx]+red[6][tx]+red[7][tx];
        invs[tx] = 1.0f / fmaxf(sqrtf(s), 1e-12f);
    }
    __syncthreads();
    #pragma unroll
    for (int r = 0; r < 4; ++r){
        int hwl = ty + r*8;
        float inv = invs[hwl];
        f16x8 h;
        #pragma unroll
        for (int e = 0; e < 8; ++e) h[e] = (_Float16)(tl[hwl][tx*8 + e] * inv);
        *(f16x8*)&Lt[((size_t)(n*HW + hw0 + hwl))*C_DIM + tx*8] = h;
    }
}

// ======== GEMM1 + first column sums; B gathered from Lt via sidx; writes A8 + atomic S0 ========
// 3-ring, ONE barrier per K-step: {barrier; stage k+2; vmcnt(2L); read; MFMA}
__global__ __launch_bounds__(256) void k_gemm1(const _Float16* __restrict__ Lt,
                                               const int* __restrict__ sidx,
                                               unsigned* __restrict__ A8,   // K_A/4 u32 per row
                                               float* __restrict__ S0){
    __shared__ _Float16 As[3*128*32];
    __shared__ _Float16 Bs[3*128*32];
    __shared__ float colred[4][128];
    const int swz = (blockIdx.x & 7)*256 + (blockIdx.x >> 3);
    const int jb = swz & 3, mb = (swz >> 2) & 31, nb = swz >> 7;
    const int mbase = mb * 128;
    const int jbase = jb * 128;
    const int t = threadIdx.x;
    const int lane = t & 63, w = t >> 6;
    const int wm = (w >> 1)*64, wn = (w & 1)*64;
    const int l15 = lane & 15, lq = lane >> 4;

    f32x4 acc[4][4] = {};
    const _Float16* pa = Lt + ((size_t)(nb*HW + mbase))*C_DIM;

    const int r0 = t >> 2, ch = t & 3;
    const int r1 = r0 + 64;
    const int cs0 = (ch ^ ((r0 >> 1) & 3)) << 3;
    const int cs1 = (ch ^ ((r1 >> 1) & 3)) << 3;
    // indirect anchor-row bases for the B tile (gather folded into staging)
    const _Float16* pbr0 = Lt + ((size_t)(nb*HW + sidx[jbase + r0]))*C_DIM;
    const _Float16* pbr1 = Lt + ((size_t)(nb*HW + sidx[jbase + r1]))*C_DIM;

#define STAGE1(buf, kt) { int k0 = (kt)*32; \
    gload_lds16(pa + (size_t)r0*C_DIM + k0 + cs0, &As[(buf)*4096 + t*8]); \
    gload_lds16(pa + (size_t)r1*C_DIM + k0 + cs1, &As[(buf)*4096 + (256+t)*8]); \
    gload_lds16(pbr0 + k0 + cs0, &Bs[(buf)*4096 + t*8]); \
    gload_lds16(pbr1 + k0 + cs1, &Bs[(buf)*4096 + (256+t)*8]); }

    STAGE1(0, 0); STAGE1(1, 1);
    #pragma unroll
    for (int kt = 0; kt < 8; ++kt){
        __builtin_amdgcn_s_barrier();                 // all waves consumed buf (kt-1)%3
        __builtin_amdgcn_sched_barrier(0);
        if (kt < 6) STAGE1((kt+2)%3, kt+2);           // overwrite buf (kt-1)%3, now safe
        if (kt < 6)      asm volatile("s_waitcnt vmcnt(8)" ::: "memory");  // stage kt done
        else if (kt < 7) asm volatile("s_waitcnt vmcnt(4)" ::: "memory");
        else             asm volatile("s_waitcnt vmcnt(0)" ::: "memory");
        __builtin_amdgcn_sched_barrier(0);
        const int cur = kt % 3;
        f16x8 af[4], bf[4];
        #pragma unroll
        for (int mi = 0; mi < 4; ++mi){
            int r = wm + mi*16 + l15;
            af[mi] = *(const f16x8*)&As[cur*4096 + r*32 + ((lq ^ ((r>>1)&3)) << 3)];
        }
        #pragma unroll
        for (int ni = 0; ni < 4; ++ni){
            int r = wn + ni*16 + l15;
            bf[ni] = *(const f16x8*)&Bs[cur*4096 + r*32 + ((lq ^ ((r>>1)&3)) << 3)];
        }
        #pragma unroll
        for (int mi = 0; mi < 4; ++mi)
            #pragma unroll
            for (int ni = 0; ni < 4; ++ni)
                acc[mi][ni] = __builtin_amdgcn_mfma_f32_16x16x32_f16(af[mi], bf[ni], acc[mi][ni], 0, 0, 0);
    }
    float csum[4] = {0.f, 0.f, 0.f, 0.f};
    #pragma unroll
    for (int mi = 0; mi < 4; ++mi)
        #pragma unroll
        for (int r = 0; r < 4; ++r){
            int hw = mbase + wm + mi*16 + lq*4 + r;
            float e[4];
            #pragma unroll
            for (int ni = 0; ni < 4; ++ni){
                e[ni] = __expf(acc[mi][ni][r] * TEMP_INV);
                csum[ni] += e[ni];
            }
            unsigned pk;
#ifdef HW_FP8
            pk = (unsigned)__builtin_amdgcn_cvt_pk_fp8_f32(e[0], e[1], 0, false);
            pk = (unsigned)__builtin_amdgcn_cvt_pk_fp8_f32(e[2], e[3], (int)pk, true);
#else
            union { unsigned u; __hip_fp8_e4m3 b[4]; } cv;
            cv.b[0] = __hip_fp8_e4m3(e[0]); cv.b[1] = __hip_fp8_e4m3(e[1]);
            cv.b[2] = __hip_fp8_e4m3(e[2]); cv.b[3] = __hip_fp8_e4m3(e[3]);
            pk = cv.u;
#endif
            // slot layout: j = wn+ni*16+l15 -> slot = wn + l15*4 + ni (coalesced u32)
            A8[((size_t)(nb*HW + hw))*(K_A/4) + (jbase + wn)/4 + l15] = pk;
        }
    #pragma unroll
    for (int ni = 0; ni < 4; ++ni){
        float cv = csum[ni];
        cv += __shfl_xor(cv, 16);
        cv += __shfl_xor(cv, 32);
        if (lane < 16) colred[w][wn + ni*16 + l15] = cv;
    }
    __syncthreads();
    if (t < 128){
        int jj = t;
        float s = (jj < 64) ? (colred[0][jj] + colred[2][jj])
                            : (colred[1][jj] + colred[3][jj]);
        atomicAdd(&S0[jbase + vperm(jj)], s);   // slot space
    }
}

// ---------------- FUSED row+col pass on fp8 slots; v from Sprev, col sums -> atomic Snext ----------------
__global__ __launch_bounds__(256) void k_fused8(const unsigned* __restrict__ A8,
                                                const float* __restrict__ Sprev,
                                                float* __restrict__ Snext){
    __shared__ float red[4][512];
    int b = blockIdx.x;                  // 512 blocks, 128 rows each
    int tg = threadIdx.x >> 6, lane = threadIdx.x & 63;
    float vr[8];
    const float* ps = Sprev + (lane << 3);
    #pragma unroll
    for (int e = 0; e < 8; ++e) vr[e] = 128.0f / fmaxf(ps[e], EPS_SK);  // v_t = 128/S_{t-1}
    float acc[8] = {};
    for (int it = 0; it < 32; ++it){
        int i = (b << 7) + (it << 2) + tg;
        uint2 a = *(const uint2*)&A8[(size_t)i*(K_A/4) + (lane << 1)];
        float av[8];
#ifdef HW_FP8
        f32x2 p0 = __builtin_amdgcn_cvt_pk_f32_fp8((int)a.x, false);
        f32x2 p1 = __builtin_amdgcn_cvt_pk_f32_fp8((int)a.x, true);
        f32x2 p2 = __builtin_amdgcn_cvt_pk_f32_fp8((int)a.y, false);
        f32x2 p3 = __builtin_amdgcn_cvt_pk_f32_fp8((int)a.y, true);
        av[0]=p0[0]; av[1]=p0[1]; av[2]=p1[0]; av[3]=p1[1];
        av[4]=p2[0]; av[5]=p2[1]; av[6]=p3[0]; av[7]=p3[1];
#else
        union { uint2 u; __hip_fp8_e4m3 b8[8]; } cv; cv.u = a;
        #pragma unroll
        for (int e = 0; e < 8; ++e) av[e] = (float)cv.b8[e];
#endif
        float r = 0.f;
        #pragma unroll
        for (int e = 0; e < 8; ++e) r += av[e] * vr[e];
        #pragma unroll
        for (int off = 32; off; off >>= 1) r += __shfl_xor(r, off);
        float un = 1.0f / fmaxf(r, EPS_SK);       // u_t = 1/R_i (previous u cancels)
        #pragma unroll
        for (int e = 0; e < 8; ++e) acc[e] += av[e] * un;
    }
    #pragma unroll
    for (int e = 0; e < 8; ++e) red[tg][(lane<<3)+e] = acc[e];
    __syncthreads();
    if (tg == 0){
        #pragma unroll
        for (int e = 0; e < 8; ++e){
            int j = (lane<<3)+e;
            atomicAdd(&Snext[j], red[0][j]+red[1][j]+red[2][j]+red[3][j]);
        }
    }
}

// ---------------- SXv[n][c][slot] = Lt[n][p_j][c] * v4[slot]  (gather + slot K-order) ----------------
__global__ __launch_bounds__(256) void k_sxvT(const _Float16* __restrict__ Lt,
                                              const int* __restrict__ sidx,
                                              const float* __restrict__ S3,
                                              _Float16* __restrict__ SXv){
    __shared__ float tl[64][65];
    int n  = blockIdx.z;
    int j0 = blockIdx.x * 64;
    int c0 = blockIdx.y * 64;
    int tx = threadIdx.x & 63, ty = threadIdx.x >> 6;
    #pragma unroll
    for (int r = 0; r < 16; ++r){
        int jl = ty + r*4;                        // natural j within 64-block
        float vv = 128.0f / fmaxf(S3[j0 + vperm(jl)], EPS_SK);   // v4 (slot space)
        int p = sidx[j0 + jl];
        tl[jl][tx] = (float)Lt[((size_t)(n*HW + p))*C_DIM + c0 + tx] * vv;
    }
    __syncthreads();
    #pragma unroll
    for (int r = 0; r < 16; ++r){
        int cl = ty + r*4;
        // SXv[c][slot tx] = natural-j value at ivp(tx)
        SXv[((size_t)(n*C_DIM + c0 + cl))*K_A + j0 + tx] = (_Float16)tl[ivp(tx) & 63][cl];
    }
}

// ======== GEMM2 + final row-normalize; B from A8 (fp8 LDS); 1-barrier ring schedule ========
__global__ __launch_bounds__(256) void k_gemm2(const _Float16* __restrict__ SXv,
                                               const unsigned* __restrict__ A8,
                                               const float* __restrict__ S3,
                                               float* __restrict__ out){
    __shared__ _Float16 As[3*128*32];            // 24 KB
    __shared__ unsigned char Bs8[3*128*32];      // 12 KB (fp8)
    __shared__ _Float16 vsh[512];
    const int swz = (blockIdx.x & 7)*128 + (blockIdx.x >> 3);
    const int mb = swz & 1, nbi = (swz >> 1) & 31, nb = swz >> 6;
    const int mbase = mb * 128;    // c
    const int nbase = nbi * 128;   // hw
    const int t = threadIdx.x;
    const int lane = t & 63, w = t >> 6;
    const int wm = (w >> 1)*64, wn = (w & 1)*64;
    const int l15 = lane & 15, lq = lane >> 4;

    vsh[t]       = (_Float16)(128.0f / fmaxf(S3[t],       EPS_SK));  // v4, slot space
    vsh[t + 256] = (_Float16)(128.0f / fmaxf(S3[t + 256], EPS_SK));

    f32x4 acc[4][4] = {};
    f32x4 racc[4] = {};
    const _Float16* pa = SXv + ((size_t)(nb*C_DIM + mbase))*K_A;
    const unsigned char* pb8 = (const unsigned char*)(A8 + ((size_t)(nb*HW + nbase))*(K_A/4));

    const int r0 = t >> 2, ch = t & 3;
    const int r1 = r0 + 64;
    const int cs0 = (ch ^ ((r0 >> 1) & 3)) << 3;
    const int cs1 = (ch ^ ((r1 >> 1) & 3)) << 3;
    const int br = t >> 1, bh = (t & 1) * 16;    // B stage: row, 16B half of 32B row-chunk

#define STAGE2(buf, kt) { int k0 = (kt)*32; \
    gload_lds16(pa + (size_t)r0*K_A + k0 + cs0, &As[(buf)*4096 + t*8]); \
    gload_lds16(pa + (size_t)r1*K_A + k0 + cs1, &As[(buf)*4096 + (256+t)*8]); \
    gload_lds16(pb8 + (size_t)br*K_A + k0 + bh, &Bs8[(buf)*4096 + br*32 + bh]); }

    STAGE2(0, 0); STAGE2(1, 1);
    #pragma unroll
    for (int kt = 0; kt < 16; ++kt){
        __builtin_amdgcn_s_barrier();                 // all waves consumed buf (kt-1)%3
        __builtin_amdgcn_sched_barrier(0);
        if (kt < 14) STAGE2((kt+2)%3, kt+2);
        if (kt < 14)      asm volatile("s_waitcnt vmcnt(6)" ::: "memory");  // stage kt done
        else if (kt < 15) asm volatile("s_waitcnt vmcnt(3)" ::: "memory");
        else              asm volatile("s_waitcnt vmcnt(0)" ::: "memory");
        __builtin_amdgcn_sched_barrier(0);
        const int cur = kt % 3;
        f16x8 af[4], bf[4], vf;
        vf = *(const f16x8*)&vsh[kt*32 + lq*8];
        #pragma unroll
        for (int mi = 0; mi < 4; ++mi){
            int r = wm + mi*16 + l15;
            af[mi] = *(const f16x8*)&As[cur*4096 + r*32 + ((lq ^ ((r>>1)&3)) << 3)];
        }
        #pragma unroll
        for (int ni = 0; ni < 4; ++ni){
            int r = wn + ni*16 + l15;
            uint2 b8 = *(const uint2*)&Bs8[cur*4096 + r*32 + lq*8];
            bf[ni] = fp8x8_to_f16x8(b8);
        }
        #pragma unroll
        for (int mi = 0; mi < 4; ++mi)
            #pragma unroll
            for (int ni = 0; ni < 4; ++ni)
                acc[mi][ni] = __builtin_amdgcn_mfma_f32_16x16x32_f16(af[mi], bf[ni], acc[mi][ni], 0, 0, 0);
        #pragma unroll
        for (int ni = 0; ni < 4; ++ni)
            racc[ni] = __builtin_amdgcn_mfma_f32_16x16x32_f16(vf, bf[ni], racc[ni], 0, 0, 0);
    }
    float un[4];
    #pragma unroll
    for (int ni = 0; ni < 4; ++ni)
        un[ni] = 1.0f / fmaxf(racc[ni][0], EPS_SK);   // u4 = 1/R4, exact vs fp8 weights
    #pragma unroll
    for (int mi = 0; mi < 4; ++mi)
        #pragma unroll
        for (int ni = 0; ni < 4; ++ni)
            #pragma unroll
            for (int r = 0; r < 4; ++r){
                int c  = mbase + wm + mi*16 + lq*4 + r;
                int hw = nbase + wn + ni*16 + l15;
                out[((size_t)(nb*C_DIM + c))*HW + hw] = acc[mi][ni][r] * un[ni];
            }
}

extern "C" void kernel_launch(void* const* d_in, const int* in_sizes, int n_in,
                              void* d_out, int out_size, void* d_ws, size_t ws_size,
                              hipStream_t stream){
    const float* x  = (const float*)d_in[0];
    const int* sidx = (const int*)d_in[1];
    float* out = (float*)d_out;

    char* ws = (char*)d_ws;
    _Float16* Lt  = (_Float16*)ws;   ws += (size_t)N_B*HW*C_DIM*2;   // 32 MiB
    unsigned* A8  = (unsigned*)ws;   ws += (size_t)M_TOT*K_A;        // 32 MiB (fp8 slots)
    _Float16* SXv = (_Float16*)ws;   ws += (size_t)N_B*C_DIM*K_A*2;  // 4 MiB (slot layout)
    float*    S   = (float*)ws;      ws += (size_t)4*K_A*4;          // S0..S3 col-sum accumulators

    k_normtrans<<<2048, 256, 0, stream>>>(x, Lt, S);      // also zeros S
    k_gemm1    <<<2048, 256, 0, stream>>>(Lt, sidx, A8, S + 0*K_A);

    // Sinkhorn middle: v_t = 128/S_{t-1} computed on the fly; col sums via device atomics
    for (int it = 0; it < 3; ++it)
        k_fused8<<<512, 256, 0, stream>>>(A8, S + it*K_A, S + (it+1)*K_A);

    k_sxvT <<<dim3(8,4,16), 256, 0, stream>>>(Lt, sidx, S + 3*K_A, SXv);
    k_gemm2<<<1024, 256, 0, stream>>>(SXv, A8, S + 3*K_A, out);
}

// Round 18
// 139.651 us; speedup vs baseline: 2.9772x; 2.9772x over previous
//
#include <hip/hip_runtime.h>
#include <hip/hip_bf16.h>
#include <hip/hip_fp16.h>
#include <hip/hip_fp8.h>

#define N_B 16
#define C_DIM 256
#define HW 4096
#define M_TOT (N_B*HW)          // 65536 global rows
#define K_A 512
#define TEMP_INV (1.0f/0.3f)
#define EPS_SK 1e-12f

typedef _Float16 f16x8 __attribute__((ext_vector_type(8)));
typedef _Float16 f16x4 __attribute__((ext_vector_type(4)));
typedef float f32x4 __attribute__((ext_vector_type(4)));
typedef float f32x2 __attribute__((ext_vector_type(2)));

#if defined(__has_builtin)
#if __has_builtin(__builtin_amdgcn_cvt_pk_fp8_f32) && __has_builtin(__builtin_amdgcn_cvt_pk_f32_fp8)
#define HW_FP8 1
#endif
#endif

// natural column j -> stored slot (4x16 transpose within each 64-block); A8, v, part, SXv
// all live in slot space. gemm2 contracts in slot order on BOTH operands -> exact.
__device__ __forceinline__ int vperm(int j){
    return (j & ~63) | ((j & 15) << 2) | ((j & 63) >> 4);
}
// inverse: slot -> natural j within the 64-block
__device__ __forceinline__ int ivp(int s){
    return (s & ~63) | ((s & 3) << 4) | ((s & 63) >> 2);
}

#define GLOBAL_AS __attribute__((address_space(1)))
#define LDS_AS __attribute__((address_space(3)))
__device__ __forceinline__ void gload_lds16(const void* g, void* l){
    __builtin_amdgcn_global_load_lds((GLOBAL_AS const void*)g, (LDS_AS void*)l, 16, 0, 0);
}

// decode 8 fp8 (uint2) -> f16x8, exact (e4m3 values are exactly representable in fp16)
__device__ __forceinline__ f16x8 fp8x8_to_f16x8(uint2 a){
    f16x8 h;
#ifdef HW_FP8
    f32x2 q0 = __builtin_amdgcn_cvt_pk_f32_fp8((int)a.x, false);
    f32x2 q1 = __builtin_amdgcn_cvt_pk_f32_fp8((int)a.x, true);
    f32x2 q2 = __builtin_amdgcn_cvt_pk_f32_fp8((int)a.y, false);
    f32x2 q3 = __builtin_amdgcn_cvt_pk_f32_fp8((int)a.y, true);
    h[0]=(_Float16)q0[0]; h[1]=(_Float16)q0[1]; h[2]=(_Float16)q1[0]; h[3]=(_Float16)q1[1];
    h[4]=(_Float16)q2[0]; h[5]=(_Float16)q2[1]; h[6]=(_Float16)q3[0]; h[7]=(_Float16)q3[1];
#else
    union { uint2 u; __hip_fp8_e4m3 b8[8]; } cv; cv.u = a;
    #pragma unroll
    for (int e = 0; e < 8; ++e) h[e] = (_Float16)(float)cv.b8[e];
#endif
    return h;
}

// ---------------- fused: read x once -> L2 norm -> Lt[n][hw][c] fp16; init v=1 ----------------
__global__ __launch_bounds__(256) void k_normtrans(const float* __restrict__ x,
                                                   _Float16* __restrict__ Lt,
                                                   float* __restrict__ v){
    __shared__ float tl[32][257];
    __shared__ float red[8][32];
    __shared__ float invs[32];
    int n   = blockIdx.x >> 7;           // 2048 blocks: 16 n x 128 hw-chunks of 32
    int hw0 = (blockIdx.x & 127) * 32;
    if (blockIdx.x < 2) v[blockIdx.x*256 + threadIdx.x] = 1.0f;
    int tx4 = threadIdx.x & 7;           // hw quad
    int cy  = threadIdx.x >> 3;          // 0..31
    const float* px = x + ((size_t)(n*C_DIM + cy))*HW + hw0 + tx4*4;
    #pragma unroll
    for (int r = 0; r < 8; ++r){
        float4 xv = *(const float4*)(px + (size_t)(r*32)*HW);
        int c = cy + r*32;
        tl[tx4*4+0][c] = xv.x;
        tl[tx4*4+1][c] = xv.y;
        tl[tx4*4+2][c] = xv.z;
        tl[tx4*4+3][c] = xv.w;
    }
    __syncthreads();
    int tx = threadIdx.x & 31, ty = threadIdx.x >> 5;   // ty 0..7
    float ss = 0.f;
    #pragma unroll
    for (int cc = 0; cc < 32; ++cc){
        float tv = tl[tx][cc*8 + ty];
        ss += tv*tv;
    }
    red[ty][tx] = ss;
    __syncthreads();
    if (ty == 0){
        float s = red[0][tx]+red[1][tx]+red[2][tx]+red[3][tx]
                + red[4][tx]+red[5][tx]+red[6][tx]+red[7][tx];
        invs[tx] = 1.0f / fmaxf(sqrtf(s), 1e-12f);
    }
    __syncthreads();
    #pragma unroll
    for (int r = 0; r < 4; ++r){
        int hwl = ty + r*8;
        float inv = invs[hwl];
        f16x8 h;
        #pragma unroll
        for (int e = 0; e < 8; ++e) h[e] = (_Float16)(tl[hwl][tx*8 + e] * inv);
        *(f16x8*)&Lt[((size_t)(n*HW + hw0 + hwl))*C_DIM + tx*8] = h;
    }
}

// ======== GEMM1 + first column partials; B gathered from Lt via sidx; writes A8 + part ========
// 3-ring, ONE barrier per K-step: {barrier; stage k+2; vmcnt(2L); read; MFMA}
__global__ __launch_bounds__(256) void k_gemm1(const _Float16* __restrict__ Lt,
                                               const int* __restrict__ sidx,
                                               unsigned* __restrict__ A8,   // K_A/4 u32 per row
                                               float* __restrict__ part){
    __shared__ _Float16 As[3*128*32];
    __shared__ _Float16 Bs[3*128*32];
    __shared__ float colred[4][128];
    const int swz = (blockIdx.x & 7)*256 + (blockIdx.x >> 3);
    const int jb = swz & 3, mb = (swz >> 2) & 31, nb = swz >> 7;
    const int mbase = mb * 128;
    const int jbase = jb * 128;
    const int t = threadIdx.x;
    const int lane = t & 63, w = t >> 6;
    const int wm = (w >> 1)*64, wn = (w & 1)*64;
    const int l15 = lane & 15, lq = lane >> 4;

    f32x4 acc[4][4] = {};
    const _Float16* pa = Lt + ((size_t)(nb*HW + mbase))*C_DIM;

    const int r0 = t >> 2, ch = t & 3;
    const int r1 = r0 + 64;
    const int cs0 = (ch ^ ((r0 >> 1) & 3)) << 3;
    const int cs1 = (ch ^ ((r1 >> 1) & 3)) << 3;
    // indirect anchor-row bases for the B tile (gather folded into staging)
    const _Float16* pbr0 = Lt + ((size_t)(nb*HW + sidx[jbase + r0]))*C_DIM;
    const _Float16* pbr1 = Lt + ((size_t)(nb*HW + sidx[jbase + r1]))*C_DIM;

#define STAGE1(buf, kt) { int k0 = (kt)*32; \
    gload_lds16(pa + (size_t)r0*C_DIM + k0 + cs0, &As[(buf)*4096 + t*8]); \
    gload_lds16(pa + (size_t)r1*C_DIM + k0 + cs1, &As[(buf)*4096 + (256+t)*8]); \
    gload_lds16(pbr0 + k0 + cs0, &Bs[(buf)*4096 + t*8]); \
    gload_lds16(pbr1 + k0 + cs1, &Bs[(buf)*4096 + (256+t)*8]); }

    STAGE1(0, 0); STAGE1(1, 1);
    #pragma unroll
    for (int kt = 0; kt < 8; ++kt){
        __builtin_amdgcn_s_barrier();                 // all waves consumed buf (kt-1)%3
        __builtin_amdgcn_sched_barrier(0);
        if (kt < 6) STAGE1((kt+2)%3, kt+2);           // overwrite buf (kt-1)%3, now safe
        if (kt < 6)      asm volatile("s_waitcnt vmcnt(8)" ::: "memory");  // stage kt done
        else if (kt < 7) asm volatile("s_waitcnt vmcnt(4)" ::: "memory");
        else             asm volatile("s_waitcnt vmcnt(0)" ::: "memory");
        __builtin_amdgcn_sched_barrier(0);
        const int cur = kt % 3;
        f16x8 af[4], bf[4];
        #pragma unroll
        for (int mi = 0; mi < 4; ++mi){
            int r = wm + mi*16 + l15;
            af[mi] = *(const f16x8*)&As[cur*4096 + r*32 + ((lq ^ ((r>>1)&3)) << 3)];
        }
        #pragma unroll
        for (int ni = 0; ni < 4; ++ni){
            int r = wn + ni*16 + l15;
            bf[ni] = *(const f16x8*)&Bs[cur*4096 + r*32 + ((lq ^ ((r>>1)&3)) << 3)];
        }
        #pragma unroll
        for (int mi = 0; mi < 4; ++mi)
            #pragma unroll
            for (int ni = 0; ni < 4; ++ni)
                acc[mi][ni] = __builtin_amdgcn_mfma_f32_16x16x32_f16(af[mi], bf[ni], acc[mi][ni], 0, 0, 0);
    }
    float csum[4] = {0.f, 0.f, 0.f, 0.f};
    #pragma unroll
    for (int mi = 0; mi < 4; ++mi)
        #pragma unroll
        for (int r = 0; r < 4; ++r){
            int hw = mbase + wm + mi*16 + lq*4 + r;
            float e[4];
            #pragma unroll
            for (int ni = 0; ni < 4; ++ni){
                e[ni] = __expf(acc[mi][ni][r] * TEMP_INV);
                csum[ni] += e[ni];
            }
            unsigned pk;
#ifdef HW_FP8
            pk = (unsigned)__builtin_amdgcn_cvt_pk_fp8_f32(e[0], e[1], 0, false);
            pk = (unsigned)__builtin_amdgcn_cvt_pk_fp8_f32(e[2], e[3], (int)pk, true);
#else
            union { unsigned u; __hip_fp8_e4m3 b[4]; } cv;
            cv.b[0] = __hip_fp8_e4m3(e[0]); cv.b[1] = __hip_fp8_e4m3(e[1]);
            cv.b[2] = __hip_fp8_e4m3(e[2]); cv.b[3] = __hip_fp8_e4m3(e[3]);
            pk = cv.u;
#endif
            // slot layout: j = wn+ni*16+l15 -> slot = wn + l15*4 + ni (coalesced u32)
            A8[((size_t)(nb*HW + hw))*(K_A/4) + (jbase + wn)/4 + l15] = pk;
        }
    #pragma unroll
    for (int ni = 0; ni < 4; ++ni){
        float cv = csum[ni];
        cv += __shfl_xor(cv, 16);
        cv += __shfl_xor(cv, 32);
        if (lane < 16) colred[w][wn + ni*16 + l15] = cv;
    }
    __syncthreads();
    if (t < 128){
        int jj = t;
        float s = (jj < 64) ? (colred[0][jj] + colred[2][jj])
                            : (colred[1][jj] + colred[3][jj]);
        part[((size_t)(nb*32 + mb))*K_A + jbase + vperm(jj)] = s;   // slot space, plain store
    }
}

// v[j] <- 128 * v[j] / max(v[j]*S_j, EPS)  — elementwise in slot space
__global__ __launch_bounds__(64) void k_colfinish(const float* __restrict__ part,
                                                  float* __restrict__ v, int nchunks){
    int j = blockIdx.x;
    int lane = threadIdx.x;
    float s = 0.f;
    for (int r = lane; r < nchunks; r += 64) s += part[(size_t)r*K_A + j];
    #pragma unroll
    for (int off = 32; off; off >>= 1) s += __shfl_xor(s, off);
    if (lane == 0){
        float vo = v[j];
        v[j] = 128.0f * vo / fmaxf(vo * s, EPS_SK);
    }
}

// ---------------- FUSED row+col pass on fp8 slots (u pass-local: u=1/R); plain part stores ----------------
__global__ __launch_bounds__(256) void k_fused8(const unsigned* __restrict__ A8,
                                                const float* __restrict__ v,
                                                float* __restrict__ part){
    __shared__ float red[4][512];
    int b = blockIdx.x;                  // 1024 blocks, 64 rows each
    int tg = threadIdx.x >> 6, lane = threadIdx.x & 63;
    float vr[8];
    const float* pv = v + (lane << 3);
    #pragma unroll
    for (int e = 0; e < 8; ++e) vr[e] = pv[e];
    float acc[8] = {};
    for (int it = 0; it < 16; ++it){
        int i = (b << 6) + (it << 2) + tg;
        uint2 a = *(const uint2*)&A8[(size_t)i*(K_A/4) + (lane << 1)];
        float av[8];
#ifdef HW_FP8
        f32x2 p0 = __builtin_amdgcn_cvt_pk_f32_fp8((int)a.x, false);
        f32x2 p1 = __builtin_amdgcn_cvt_pk_f32_fp8((int)a.x, true);
        f32x2 p2 = __builtin_amdgcn_cvt_pk_f32_fp8((int)a.y, false);
        f32x2 p3 = __builtin_amdgcn_cvt_pk_f32_fp8((int)a.y, true);
        av[0]=p0[0]; av[1]=p0[1]; av[2]=p1[0]; av[3]=p1[1];
        av[4]=p2[0]; av[5]=p2[1]; av[6]=p3[0]; av[7]=p3[1];
#else
        union { uint2 u; __hip_fp8_e4m3 b8[8]; } cv; cv.u = a;
        #pragma unroll
        for (int e = 0; e < 8; ++e) av[e] = (float)cv.b8[e];
#endif
        float r = 0.f;
        #pragma unroll
        for (int e = 0; e < 8; ++e) r += av[e] * vr[e];
        #pragma unroll
        for (int off = 32; off; off >>= 1) r += __shfl_xor(r, off);
        float un = 1.0f / fmaxf(r, EPS_SK);       // u_t = 1/R_i (previous u cancels)
        #pragma unroll
        for (int e = 0; e < 8; ++e) acc[e] += av[e] * un;
    }
    #pragma unroll
    for (int e = 0; e < 8; ++e) red[tg][(lane<<3)+e] = acc[e];
    __syncthreads();
    if (tg == 0){
        #pragma unroll
        for (int e = 0; e < 8; ++e){
            int j = (lane<<3)+e;
            part[((size_t)b)*K_A + j] = red[0][j]+red[1][j]+red[2][j]+red[3][j];
        }
    }
}

// ---------------- SXv[n][c][slot] = Lt[n][p_j][c] * v4[slot]  (gather + slot K-order) ----------------
__global__ __launch_bounds__(256) void k_sxvT(const _Float16* __restrict__ Lt,
                                              const int* __restrict__ sidx,
                                              const float* __restrict__ v,
                                              _Float16* __restrict__ SXv){
    __shared__ float tl[64][65];
    int n  = blockIdx.z;
    int j0 = blockIdx.x * 64;
    int c0 = blockIdx.y * 64;
    int tx = threadIdx.x & 63, ty = threadIdx.x >> 6;
    #pragma unroll
    for (int r = 0; r < 16; ++r){
        int jl = ty + r*4;                        // natural j within 64-block
        float vv = v[j0 + vperm(jl)];             // v4 (slot space)
        int p = sidx[j0 + jl];
        tl[jl][tx] = (float)Lt[((size_t)(n*HW + p))*C_DIM + c0 + tx] * vv;
    }
    __syncthreads();
    #pragma unroll
    for (int r = 0; r < 16; ++r){
        int cl = ty + r*4;
        // SXv[c][slot tx] = natural-j value at ivp(tx)
        SXv[((size_t)(n*C_DIM + c0 + cl))*K_A + j0 + tx] = (_Float16)tl[ivp(tx) & 63][cl];
    }
}

// ======== GEMM2 + final row-normalize; B from A8 (fp8 LDS); 1-barrier ring schedule ========
__global__ __launch_bounds__(256) void k_gemm2(const _Float16* __restrict__ SXv,
                                               const unsigned* __restrict__ A8,
                                               const float* __restrict__ v,
                                               float* __restrict__ out){
    __shared__ _Float16 As[3*128*32];            // 24 KB
    __shared__ unsigned char Bs8[3*128*32];      // 12 KB (fp8)
    __shared__ _Float16 vsh[512];
    const int swz = (blockIdx.x & 7)*128 + (blockIdx.x >> 3);
    const int mb = swz & 1, nbi = (swz >> 1) & 31, nb = swz >> 6;
    const int mbase = mb * 128;    // c
    const int nbase = nbi * 128;   // hw
    const int t = threadIdx.x;
    const int lane = t & 63, w = t >> 6;
    const int wm = (w >> 1)*64, wn = (w & 1)*64;
    const int l15 = lane & 15, lq = lane >> 4;

    vsh[t]       = (_Float16)v[t];          // v in slot space == A8/SXv K-order
    vsh[t + 256] = (_Float16)v[t + 256];

    f32x4 acc[4][4] = {};
    f32x4 racc[4] = {};
    const _Float16* pa = SXv + ((size_t)(nb*C_DIM + mbase))*K_A;
    const unsigned char* pb8 = (const unsigned char*)(A8 + ((size_t)(nb*HW + nbase))*(K_A/4));

    const int r0 = t >> 2, ch = t & 3;
    const int r1 = r0 + 64;
    const int cs0 = (ch ^ ((r0 >> 1) & 3)) << 3;
    const int cs1 = (ch ^ ((r1 >> 1) & 3)) << 3;
    const int br = t >> 1, bh = (t & 1) * 16;    // B stage: row, 16B half of 32B row-chunk

#define STAGE2(buf, kt) { int k0 = (kt)*32; \
    gload_lds16(pa + (size_t)r0*K_A + k0 + cs0, &As[(buf)*4096 + t*8]); \
    gload_lds16(pa + (size_t)r1*K_A + k0 + cs1, &As[(buf)*4096 + (256+t)*8]); \
    gload_lds16(pb8 + (size_t)br*K_A + k0 + bh, &Bs8[(buf)*4096 + br*32 + bh]); }

    STAGE2(0, 0); STAGE2(1, 1);
    #pragma unroll
    for (int kt = 0; kt < 16; ++kt){
        __builtin_amdgcn_s_barrier();                 // all waves consumed buf (kt-1)%3
        __builtin_amdgcn_sched_barrier(0);
        if (kt < 14) STAGE2((kt+2)%3, kt+2);
        if (kt < 14)      asm volatile("s_waitcnt vmcnt(6)" ::: "memory");  // stage kt done
        else if (kt < 15) asm volatile("s_waitcnt vmcnt(3)" ::: "memory");
        else              asm volatile("s_waitcnt vmcnt(0)" ::: "memory");
        __builtin_amdgcn_sched_barrier(0);
        const int cur = kt % 3;
        f16x8 af[4], bf[4], vf;
        vf = *(const f16x8*)&vsh[kt*32 + lq*8];
        #pragma unroll
        for (int mi = 0; mi < 4; ++mi){
            int r = wm + mi*16 + l15;
            af[mi] = *(const f16x8*)&As[cur*4096 + r*32 + ((lq ^ ((r>>1)&3)) << 3)];
        }
        #pragma unroll
        for (int ni = 0; ni < 4; ++ni){
            int r = wn + ni*16 + l15;
            uint2 b8 = *(const uint2*)&Bs8[cur*4096 + r*32 + lq*8];
            bf[ni] = fp8x8_to_f16x8(b8);
        }
        #pragma unroll
        for (int mi = 0; mi < 4; ++mi)
            #pragma unroll
            for (int ni = 0; ni < 4; ++ni)
                acc[mi][ni] = __builtin_amdgcn_mfma_f32_16x16x32_f16(af[mi], bf[ni], acc[mi][ni], 0, 0, 0);
        #pragma unroll
        for (int ni = 0; ni < 4; ++ni)
            racc[ni] = __builtin_amdgcn_mfma_f32_16x16x32_f16(vf, bf[ni], racc[ni], 0, 0, 0);
    }
    float un[4];
    #pragma unroll
    for (int ni = 0; ni < 4; ++ni)
        un[ni] = 1.0f / fmaxf(racc[ni][0], EPS_SK);   // u4 = 1/R4, exact vs fp8 weights
    #pragma unroll
    for (int mi = 0; mi < 4; ++mi)
        #pragma unroll
        for (int ni = 0; ni < 4; ++ni)
            #pragma unroll
            for (int r = 0; r < 4; ++r){
                int c  = mbase + wm + mi*16 + lq*4 + r;
                int hw = nbase + wn + ni*16 + l15;
                out[((size_t)(nb*C_DIM + c))*HW + hw] = acc[mi][ni][r] * un[ni];
            }
}

extern "C" void kernel_launch(void* const* d_in, const int* in_sizes, int n_in,
                              void* d_out, int out_size, void* d_ws, size_t ws_size,
                              hipStream_t stream){
    const float* x  = (const float*)d_in[0];
    const int* sidx = (const int*)d_in[1];
    float* out = (float*)d_out;

    char* ws = (char*)d_ws;
    _Float16* Lt  = (_Float16*)ws;   ws += (size_t)N_B*HW*C_DIM*2;   // 32 MiB
    unsigned* A8  = (unsigned*)ws;   ws += (size_t)M_TOT*K_A;        // 32 MiB (fp8 slots)
    _Float16* SXv = (_Float16*)ws;   ws += (size_t)N_B*C_DIM*K_A*2;  // 4 MiB (slot layout)
    float*    v   = (float*)ws;      ws += (size_t)K_A*4;
    float*    part= (float*)ws;      ws += (size_t)1024*K_A*4;       // 2 MiB

    k_normtrans<<<2048, 256, 0, stream>>>(x, Lt, v);
    k_gemm1    <<<2048, 256, 0, stream>>>(Lt, sidx, A8, part);

    k_colfinish<<<512, 64, 0, stream>>>(part, v, 512);        // v1 (slot space)
    for (int it = 0; it < 3; ++it){
        k_fused8   <<<1024, 256, 0, stream>>>(A8, v, part);   // u_t local, S_{t+1}
        k_colfinish<<<512, 64, 0, stream>>>(part, v, 1024);   // v_{t+1}
    }

    k_sxvT <<<dim3(8,4,16), 256, 0, stream>>>(Lt, sidx, v, SXv);
    k_gemm2<<<1024, 256, 0, stream>>>(SXv, A8, v, out);
}